// Round 27
// baseline (231.370 us; speedup 1.0000x reference)
//
#include <hip/hip_runtime.h>

// Problem constants
#define HD    16
#define DH    128
#define BB    2
#define SS    2048
#define DM    2048
#define NQKV  6144   // 3*HD*DH
#define MTOT  4096   // BB*SS

typedef short   bfx8  __attribute__((ext_vector_type(8)));   // 8 bf16 (4 VGPRs)
typedef float   f32x4 __attribute__((ext_vector_type(4)));

__device__ __forceinline__ unsigned short f2bf(float f) {
  union { float f; unsigned int u; } c; c.f = f;
  unsigned int u = c.u + 0x7FFFu + ((c.u >> 16) & 1u);
  return (unsigned short)(u >> 16);
}

__device__ __forceinline__ void gload_lds16(const unsigned short* g, unsigned short* l) {
  __builtin_amdgcn_global_load_lds(
      (const __attribute__((address_space(1))) unsigned int*)g,
      (__attribute__((address_space(3))) unsigned int*)l, 16, 0, 0);
}

// DRAINED barrier: lgkmcnt(0) before s_barrier guarantees all issued ds_reads have
// executed before any wave passes -> post-barrier global_load_lds stages cannot
// overwrite LDS regions still pending read.
#define BARS() do { asm volatile("s_waitcnt lgkmcnt(0)" ::: "memory");               \
                    __builtin_amdgcn_sched_barrier(0); __builtin_amdgcn_s_barrier(); \
                    __builtin_amdgcn_sched_barrier(0); } while (0)
#define VMCNT7() do { asm volatile("s_waitcnt vmcnt(7)" ::: "memory"); \
                      __builtin_amdgcn_sched_barrier(0); } while (0)
#define VMCNT6() do { asm volatile("s_waitcnt vmcnt(6)" ::: "memory"); \
                      __builtin_amdgcn_sched_barrier(0); } while (0)

// ---------------- fused prep: f32->bf16 cast (blocks 0..8191) + w_in transpose ----------------
// blocks [8192, 20480): w_in [2048][6144] f32 -> Wit [6144][2048] bf16 (32x32 LDS tiles)
__global__ __launch_bounds__(256) void prep_fused_k(const float* __restrict__ x,
                                                    unsigned short* __restrict__ Xb,
                                                    const float* __restrict__ w_in,
                                                    unsigned short* __restrict__ Wit) {
  __shared__ float t[32][33];
  const int bid = (int)blockIdx.x;
  if (bid < 8192) {
    // cast: n4 = 4096*2048/4 = 2097152 = 8192*256 exactly
    const int i = bid * 256 + (int)threadIdx.x;
    const float4 v = *(const float4*)(x + (size_t)i * 4);
    ushort4 o;
    o.x = f2bf(v.x); o.y = f2bf(v.y); o.z = f2bf(v.z); o.w = f2bf(v.w);
    *(ushort4*)(Xb + (size_t)i * 4) = o;
    return;
  }
  // transpose w_in: R=DM rows, C=NQKV cols; tile grid (192 c-tiles x 64 r-tiles)
  const int tb = bid - 8192;
  const int c0 = (tb % 192) * 32, r0 = (tb / 192) * 32;
  const int tx = threadIdx.x & 31, ty = threadIdx.x >> 5;  // 32 x 8
#pragma unroll
  for (int i = 0; i < 4; i++) {
    int r = r0 + ty + i * 8;
    t[ty + i * 8][tx] = w_in[(size_t)r * NQKV + c0 + tx];
  }
  __syncthreads();
#pragma unroll
  for (int i = 0; i < 4; i++) {
    int c = c0 + ty + i * 8;
    Wit[(size_t)c * DM + r0 + tx] = f2bf(t[tx][ty + i * 8]);
  }
}

// ---------------- 256x192 bf16 GEMM for QKV: 4M x 2N wave grid, fully drained ----
__global__ __launch_bounds__(512, 2) void gemm256_qkv_k(const unsigned short* __restrict__ A,
                                                        const unsigned short* __restrict__ Bt,
                                                        unsigned short* __restrict__ Qg,
                                                        unsigned short* __restrict__ Kg,
                                                        unsigned short* __restrict__ Vg,
                                                        int K) {
  __shared__ __align__(16) unsigned short Asb[2][256 * 64];  // 64 KB
  __shared__ __align__(16) unsigned short Bsb[2][192 * 64];  // 48 KB
  const int tid = threadIdx.x;
  const int lane = tid & 63, wid = tid >> 6;
  const int wr = wid >> 1, wc = wid & 1;            // 4 x 2 wave grid
  const int cbase = lane & 15, rgrp = lane >> 4;
  const int bid = (int)blockIdx.x;
  const int id = (bid & 7) * 64 + (bid >> 3);       // XCD-bijective (512 = 8*64)
  const int nb = id >> 4, mb = id & 15;
  const size_t m0 = (size_t)mb * 256, n0 = (size_t)nb * 192;
  const int nkt = K >> 6;                           // 32 K-tiles (even)

#define STAGE_A64(u_, g_) do {                                                          \
    const int uc_ = ((u_) < nkt ? (u_) : (nkt - 1));                                    \
    const int r_ = tid >> 3, s_ = tid & 7;                                              \
    gload_lds16(A + (m0 + (g_) * 64 + r_) * (size_t)K + uc_ * 64 +                      \
                    (((s_ * 16) ^ ((r_ & 7) << 4)) >> 1),                               \
                &Asb[(u_) & 1][(g_) * 4096] + tid * 8); } while (0)
#define STAGE_B64(u_, g_) do {                                                          \
    const int uc_ = ((u_) < nkt ? (u_) : (nkt - 1));                                    \
    const int r_ = tid >> 3, s_ = tid & 7;                                              \
    gload_lds16(Bt + (n0 + (g_) * 64 + r_) * (size_t)K + uc_ * 64 +                     \
                    (((s_ * 16) ^ ((r_ & 7) << 4)) >> 1),                               \
                &Bsb[(u_) & 1][(g_) * 4096] + tid * 8); } while (0)

  const int axor = (cbase & 7) << 4;
  int a_off[2], b_off[2];
#pragma unroll
  for (int ks = 0; ks < 2; ks++) {
    a_off[ks] = ((wr * 64 + cbase) * 128 + ((ks * 64 + rgrp * 16) ^ axor)) >> 1;
    b_off[ks] = ((wc * 96 + cbase) * 128 + ((ks * 64 + rgrp * 16) ^ axor)) >> 1;
  }

#define RD_AALL(dst_, p_) do { _Pragma("unroll")                                         \
    for (int mf_ = 0; mf_ < 4; mf_++) { _Pragma("unroll")                                \
      for (int ks_ = 0; ks_ < 2; ks_++)                                                  \
        dst_[mf_][ks_] = *(const bfx8*)((p_) + a_off[ks_] + mf_ * 1024); } } while (0)
#define RD_BP(dst_, p_, P_) do { _Pragma("unroll")                                       \
    for (int nf_ = 0; nf_ < 2; nf_++) { _Pragma("unroll")                                \
      for (int ks_ = 0; ks_ < 2; ks_++)                                                  \
        dst_[nf_][ks_] = *(const bfx8*)((p_) + b_off[ks_] + (nf_ + (P_)) * 1024); } } while (0)

#define MFMA_P(no_, AF_, BF_) do {                                                       \
    __builtin_amdgcn_s_setprio(1);                                                      \
    _Pragma("unroll")                                                                    \
    for (int mf_ = 0; mf_ < 4; mf_++) { _Pragma("unroll")                                \
      for (int nf_ = 0; nf_ < 2; nf_++) { _Pragma("unroll")                              \
        for (int ks_ = 0; ks_ < 2; ks_++)                                                \
          acc[mf_][nf_ + (no_)] = __builtin_amdgcn_mfma_f32_16x16x32_bf16(               \
              AF_[mf_][ks_], BF_[nf_][ks_], acc[mf_][nf_ + (no_)], 0, 0, 0); } }         \
    __builtin_amdgcn_s_setprio(0); } while (0)

  f32x4 acc[4][6];
  const f32x4 z = {0.f, 0.f, 0.f, 0.f};
#pragma unroll
  for (int mf = 0; mf < 4; mf++)
#pragma unroll
    for (int nf = 0; nf < 6; nf++) acc[mf][nf] = z;

  // prologue: stage tiles 0 and 1 fully (14 loads); vmcnt(7) -> tile 0 landed
  STAGE_A64(0, 0); STAGE_A64(0, 1); STAGE_A64(0, 2); STAGE_A64(0, 3);
  STAGE_B64(0, 0); STAGE_B64(0, 1); STAGE_B64(0, 2);
  STAGE_A64(1, 0); STAGE_A64(1, 1); STAGE_A64(1, 2); STAGE_A64(1, 3);
  STAGE_B64(1, 0); STAGE_B64(1, 1); STAGE_B64(1, 2);
  VMCNT7();
  BARS();
  bfx8 aA[4][2], b01A[2][2], aB[4][2], b01B[2][2];
  RD_AALL(aA, &Asb[0][0]);
  RD_BP(b01A, &Bsb[0][0], 0);
  BARS();   // drain prologue prefetch reads before ph1's stage into buffer 0

#define TILE_BODY(u_, Ac, B01c, An, B01n) do {                                           \
    const unsigned short* Bs_  = &Bsb[(u_) & 1][0];                                      \
    const unsigned short* Asn_ = &Asb[((u_) + 1) & 1][0];                                \
    const unsigned short* Bsn_ = &Bsb[((u_) + 1) & 1][0];                                \
    bfx8 b23[2][2], b45[2][2];                                                           \
    /* ph1: read b23(u); stage A(u+2) g0-3 (A(u) reads executed at prior drained bar) */ \
    RD_BP(b23, Bs_, 2);                                                                  \
    STAGE_A64((u_) + 2, 0); STAGE_A64((u_) + 2, 1);                                      \
    STAGE_A64((u_) + 2, 2); STAGE_A64((u_) + 2, 3);                                      \
    BARS();                                                                              \
    MFMA_P(0, Ac, B01c);                                                                 \
    /* ph2: read b45(u); stage B(u+2) g0 */                                              \
    RD_BP(b45, Bs_, 4);                                                                  \
    STAGE_B64((u_) + 2, 0);                                                              \
    BARS();                                                                              \
    MFMA_P(2, Ac, b23);                                                                  \
    /* ph3: stage B(u+2) g1,g2; vmcnt(7) -> tile u+1 resident; prefetch next A+b01 */    \
    STAGE_B64((u_) + 2, 1); STAGE_B64((u_) + 2, 2);                                      \
    VMCNT7();                                                                            \
    BARS();                                                                              \
    RD_AALL(An, Asn_);                                                                   \
    RD_BP(B01n, Bsn_, 0);                                                                \
    MFMA_P(4, Ac, b45);                                                                  \
    BARS();                                                                              \
  } while (0)

#pragma unroll 1
  for (int u = 0; u < nkt; u += 2) {
    TILE_BODY(u,     aA, b01A, aB, b01B);
    TILE_BODY(u + 1, aB, b01B, aA, b01A);
  }
#undef TILE_BODY
#undef STAGE_A64
#undef STAGE_B64

  // ---- split epilogue: n -> (head, q/k/v, d); each 16-wide frag within one class ----
#pragma unroll
  for (int mf = 0; mf < 4; mf++)
#pragma unroll
    for (int nf = 0; nf < 6; nf++) {
      const int nn = (int)n0 + wc * 96 + nf * 16;
      const int h = nn / 384, tt = (nn >> 7) % 3;
      const int d = (nn & 127) + cbase;
      const int row0 = (int)m0 + wr * 64 + mf * 16 + rgrp * 4;
      const int bb = row0 >> 11;
      const int s0 = row0 & 2047;
      if (tt == 2) {
        ushort4 v;
        v.x = f2bf(acc[mf][nf][0]); v.y = f2bf(acc[mf][nf][1]);
        v.z = f2bf(acc[mf][nf][2]); v.w = f2bf(acc[mf][nf][3]);
        *(ushort4*)(Vg + ((size_t)(bb * HD + h) * DH + d) * SS + s0) = v;
      } else {
        unsigned short* dst = (tt == 0 ? Qg : Kg);
#pragma unroll
        for (int r = 0; r < 4; r++)
          dst[((size_t)(bb * HD + h) * SS + s0 + r) * DH + d] = f2bf(acc[mf][nf][r]);
      }
    }
}

// ---------------- 256x128 bf16 GEMM for out-proj, fully drained ----------------
__global__ __launch_bounds__(512, 2) void gemm256_out_k(const unsigned short* __restrict__ A,
                                                        const unsigned short* __restrict__ Bt,
                                                        float* __restrict__ C, int K, int ldc) {
  __shared__ __align__(16) unsigned short Asb[2][256 * 64];  // 64 KB
  __shared__ __align__(16) unsigned short Bsb[2][128 * 64];  // 32 KB
  const int tid = threadIdx.x;
  const int lane = tid & 63, wid = tid >> 6;
  const int wr = wid >> 2, wc = wid & 3;            // 2 x 4 wave grid
  const int cbase = lane & 15, rgrp = lane >> 4;
  const int bid = (int)blockIdx.x;
  const int id = (bid & 7) * 32 + (bid >> 3);       // XCD-bijective (256 = 8*32)
  const int nb = id >> 4, mb = id & 15;
  const size_t m0 = (size_t)mb * 256, n0 = (size_t)nb * 128;
  const int nkt = K >> 6;                           // 32 K-tiles (even)

#define STAGE_AO(u_, g_) do {                                                           \
    const int uc_ = ((u_) < nkt ? (u_) : (nkt - 1));                                    \
    const int r_ = tid >> 3, s_ = tid & 7;                                              \
    gload_lds16(A + (m0 + (g_) * 64 + r_) * (size_t)K + uc_ * 64 +                      \
                    (((s_ * 16) ^ ((r_ & 7) << 4)) >> 1),                               \
                &Asb[(u_) & 1][(g_) * 4096] + tid * 8); } while (0)
#define STAGE_BO(u_, g_) do {                                                           \
    const int uc_ = ((u_) < nkt ? (u_) : (nkt - 1));                                    \
    const int r_ = tid >> 3, s_ = tid & 7;                                              \
    gload_lds16(Bt + (n0 + (g_) * 64 + r_) * (size_t)K + uc_ * 64 +                     \
                    (((s_ * 16) ^ ((r_ & 7) << 4)) >> 1),                               \
                &Bsb[(u_) & 1][(g_) * 4096] + tid * 8); } while (0)

  const int axor = (cbase & 7) << 4;
  int a_off[2], b_off[2];
#pragma unroll
  for (int ks = 0; ks < 2; ks++) {
    a_off[ks] = ((wr * 128 + cbase) * 128 + ((ks * 64 + rgrp * 16) ^ axor)) >> 1;
    b_off[ks] = ((wc * 32 + cbase) * 128 + ((ks * 64 + rgrp * 16) ^ axor)) >> 1;
  }

#define RD_A03(dst_, p_) do { _Pragma("unroll")                                          \
    for (int mf_ = 0; mf_ < 4; mf_++) { _Pragma("unroll")                                \
      for (int ks_ = 0; ks_ < 2; ks_++)                                                  \
        dst_[mf_][ks_] = *(const bfx8*)((p_) + a_off[ks_] + mf_ * 1024); } } while (0)
#define RD_A47(dst_, p_) do { _Pragma("unroll")                                          \
    for (int mf_ = 0; mf_ < 4; mf_++) { _Pragma("unroll")                                \
      for (int ks_ = 0; ks_ < 2; ks_++)                                                  \
        dst_[mf_][ks_] = *(const bfx8*)((p_) + a_off[ks_] + (mf_ + 4) * 1024); } } while (0)
#define RD_B01(dst_, p_) do { _Pragma("unroll")                                          \
    for (int nf_ = 0; nf_ < 2; nf_++) { _Pragma("unroll")                                \
      for (int ks_ = 0; ks_ < 2; ks_++)                                                  \
        dst_[nf_][ks_] = *(const bfx8*)((p_) + b_off[ks_] + nf_ * 1024); } } while (0)

#define MFMA_O(mo_, AF_, BF_) do {                                                       \
    __builtin_amdgcn_s_setprio(1);                                                      \
    _Pragma("unroll")                                                                    \
    for (int mf_ = 0; mf_ < 4; mf_++) { _Pragma("unroll")                                \
      for (int nf_ = 0; nf_ < 2; nf_++) { _Pragma("unroll")                              \
        for (int ks_ = 0; ks_ < 2; ks_++)                                                \
          acc[mf_ + (mo_)][nf_] = __builtin_amdgcn_mfma_f32_16x16x32_bf16(               \
              AF_[mf_][ks_], BF_[nf_][ks_], acc[mf_ + (mo_)][nf_], 0, 0, 0); } }         \
    __builtin_amdgcn_s_setprio(0); } while (0)

  f32x4 acc[8][2];
  const f32x4 z = {0.f, 0.f, 0.f, 0.f};
#pragma unroll
  for (int mf = 0; mf < 8; mf++)
#pragma unroll
    for (int nf = 0; nf < 2; nf++) acc[mf][nf] = z;

  STAGE_AO(0, 0); STAGE_AO(0, 1); STAGE_AO(0, 2); STAGE_AO(0, 3);
  STAGE_BO(0, 0); STAGE_BO(0, 1);
  STAGE_AO(1, 0); STAGE_AO(1, 1); STAGE_AO(1, 2); STAGE_AO(1, 3);
  STAGE_BO(1, 0); STAGE_BO(1, 1);
  VMCNT6();
  BARS();
  bfx8 a03A[4][2], b01A[2][2], a03B[4][2], b01B[2][2];
  RD_A03(a03A, &Asb[0][0]);
  RD_B01(b01A, &Bsb[0][0]);
  BARS();   // drain prologue prefetch reads before ph1's stage into buffer 0

#define TILE_BODY_O(u_, A03c, B01c, A03n, B01n) do {                                     \
    const unsigned short* As_  = &Asb[(u_) & 1][0];                                      \
    const unsigned short* Asn_ = &Asb[((u_) + 1) & 1][0];                                \
    const unsigned short* Bsn_ = &Bsb[((u_) + 1) & 1][0];                                \
    bfx8 a47[4][2];                                                                      \
    RD_A47(a47, As_);                                                                    \
    STAGE_AO((u_) + 2, 0); STAGE_AO((u_) + 2, 2);                                        \
    BARS();                                                                              \
    MFMA_O(0, A03c, B01c);                                                               \
    STAGE_AO((u_) + 2, 1); STAGE_AO((u_) + 2, 3);                                        \
    STAGE_BO((u_) + 2, 0); STAGE_BO((u_) + 2, 1);                                        \
    VMCNT6();                                                                            \
    BARS();                                                                              \
    RD_A03(A03n, Asn_);                                                                  \
    RD_B01(B01n, Bsn_);                                                                  \
    MFMA_O(4, a47, B01c);                                                                \
    BARS();                                                                              \
  } while (0)

#pragma unroll 1
  for (int u = 0; u < nkt; u += 2) {
    TILE_BODY_O(u,     a03A, b01A, a03B, b01B);
    TILE_BODY_O(u + 1, a03B, b01B, a03A, b01A);
  }
#undef TILE_BODY_O
#undef STAGE_AO
#undef STAGE_BO

#pragma unroll
  for (int mf = 0; mf < 8; mf++)
#pragma unroll
    for (int nf = 0; nf < 2; nf++)
#pragma unroll
      for (int r = 0; r < 4; r++) {
        size_t row = m0 + wr * 128 + mf * 16 + rgrp * 4 + r;
        size_t col = n0 + wc * 32 + nf * 16 + cbase;
        C[row * ldc + col] = acc[mf][nf][r];
      }
}

// ---------------- flash attention (blocks 0..1023) + w_out transpose tail (1024..5119) ----------
// Transpose blocks backfill CUs as attention blocks drain; Wot is consumed only by the
// LATER gemm256_out_k launch (stream order), so no intra-kernel sync is needed.
__global__ __launch_bounds__(256) void attn_wot_k(const unsigned short* __restrict__ Qg,
                                                  const unsigned short* __restrict__ Kg,
                                                  const unsigned short* __restrict__ Vg,
                                                  unsigned short* __restrict__ ao,
                                                  const float* __restrict__ w_out,
                                                  unsigned short* __restrict__ Wot) {
  __shared__ __align__(16) unsigned short Klds[2][64 * 128];   // 2 x 16 KB
  __shared__ __align__(16) unsigned short Vt[2][128 * 64];     // 2 x 16 KB
  __shared__ __align__(16) unsigned short Plds[4][16 * 64];    // 8 KB per-wave P rows
  const int tid = threadIdx.x;
  const int bid = (int)blockIdx.x;

  if (bid >= 1024) {
    // w_out transpose: [2048][2048] f32 -> Wot [2048][2048]^T bf16; t aliases Klds
    float* t = (float*)&Klds[0][0];                 // 32*33 floats = 4224 B < 32 KB
    const int tb = bid - 1024;
    const int c0 = (tb & 63) * 32, r0 = (tb >> 6) * 32;
    const int tx = tid & 31, ty = tid >> 5;         // 32 x 8
#pragma unroll
    for (int i = 0; i < 4; i++) {
      int r = r0 + ty + i * 8;
      t[(ty + i * 8) * 33 + tx] = w_out[(size_t)r * DM + c0 + tx];
    }
    __syncthreads();
#pragma unroll
    for (int i = 0; i < 4; i++) {
      int c = c0 + ty + i * 8;
      Wot[(size_t)c * DM + r0 + tx] = f2bf(t[tx * 33 + ty + i * 8]);
    }
    return;
  }

  const int lane = tid & 63, wid = tid >> 6;
  const int cbase = lane & 15, rgrp = lane >> 4;
  const int cx = (cbase & 7) << 4;

  const int bh = (bid & 7) * 4 + ((bid >> 3) & 3);
  const int qt = 31 - (bid >> 5);
  const int b = bh >> 4, h = bh & 15;
  const int qbase = qt * 64;

  const unsigned short* qp0 = Qg + (size_t)(b * HD + h) * SS * DH;
  const unsigned short* kp  = Kg + (size_t)(b * HD + h) * SS * DH;
  const unsigned short* vp  = Vg + (size_t)(b * HD + h) * DH * SS;
  const float scale = 0.08838834764831845f;
  const f32x4 z = {0.f, 0.f, 0.f, 0.f};
  const int qi = qbase + wid * 16 + cbase;

  bfx8 qf[4];
  {
    const unsigned short* qp = qp0 + (size_t)qi * DH;
#pragma unroll
    for (int ks = 0; ks < 4; ks++) qf[ks] = *(const bfx8*)(qp + ks * 32 + rgrp * 8);
  }

  float m_run = -1e30f, l_run = 0.f;
  f32x4 o[8];
#pragma unroll
  for (int mb = 0; mb < 8; mb++) o[mb] = z;

#define STAGE_T(t_, s_) do {                                                        \
    const int kvb_ = (t_) * 64;                                                     \
    _Pragma("unroll")                                                               \
    for (int i_ = 0; i_ < 4; i_++) {                                                \
      int idx_ = i_ * 256 + tid;                                                    \
      int r_ = idx_ >> 4, bo_ = (idx_ & 15) * 16;                                   \
      gload_lds16(kp + (size_t)(kvb_ + r_) * DH + ((bo_ ^ ((r_ & 7) << 4)) >> 1),   \
                  &Klds[s_][idx_ * 8]);                                             \
    }                                                                               \
    _Pragma("unroll")                                                               \
    for (int i_ = 0; i_ < 4; i_++) {                                                \
      int idx_ = i_ * 256 + tid;                                                    \
      int d_ = idx_ >> 3, bo_ = (idx_ & 7) * 16;                                    \
      gload_lds16(vp + (size_t)d_ * SS + kvb_ + ((bo_ ^ ((d_ & 7) << 4)) >> 1),     \
                  &Vt[s_][idx_ * 8]);                                               \
    } } while (0)

  const int ntiles = qt + 1;
  STAGE_T(0, 0);
  __syncthreads();

  for (int t = 0; t < ntiles; ++t) {
    const int sel = t & 1;
    if (t + 1 < ntiles) STAGE_T(t + 1, sel ^ 1);
    const unsigned short* Ks_ = &Klds[sel][0];
    const unsigned short* Vs_ = &Vt[sel][0];
    const int kvb = t * 64;

    f32x4 s[4];
#pragma unroll
    for (int mf = 0; mf < 4; mf++) s[mf] = z;
#pragma unroll
    for (int mf = 0; mf < 4; mf++)
#pragma unroll
      for (int ks = 0; ks < 4; ks++) {
        bfx8 kf = *(const bfx8*)(Ks_ + (((mf * 16 + cbase) * 256 + ((ks * 64 + rgrp * 16) ^ cx)) >> 1));
        s[mf] = __builtin_amdgcn_mfma_f32_16x16x32_bf16(kf, qf[ks], s[mf], 0, 0, 0);
      }

    float sv[4][4];
    const bool diag = (t == ntiles - 1);
#pragma unroll
    for (int mf = 0; mf < 4; mf++)
#pragma unroll
      for (int r = 0; r < 4; r++) {
        float v = s[mf][r] * scale;
        if (diag && (kvb + mf * 16 + rgrp * 4 + r > qi)) v = -1e30f;
        sv[mf][r] = v;
      }
    float tm = sv[0][0];
#pragma unroll
    for (int mf = 0; mf < 4; mf++)
#pragma unroll
      for (int r = 0; r < 4; r++) tm = fmaxf(tm, sv[mf][r]);
    tm = fmaxf(tm, __shfl_xor(tm, 16));
    tm = fmaxf(tm, __shfl_xor(tm, 32));
    const float mnew = fmaxf(m_run, tm);
    float p[4][4];
    float rs = 0.f;
#pragma unroll
    for (int mf = 0; mf < 4; mf++)
#pragma unroll
      for (int r = 0; r < 4; r++) { p[mf][r] = __expf(sv[mf][r] - mnew); rs += p[mf][r]; }
    rs += __shfl_xor(rs, 16);
    rs += __shfl_xor(rs, 32);
    const float alpha = __expf(m_run - mnew);
    l_run = l_run * alpha + rs;
    m_run = mnew;
#pragma unroll
    for (int mb = 0; mb < 8; mb++)
#pragma unroll
      for (int r = 0; r < 4; r++) o[mb][r] *= alpha;

#pragma unroll
    for (int mf = 0; mf < 4; mf++)
#pragma unroll
      for (int rr = 0; rr < 2; rr++) {
        unsigned int pp = (unsigned int)f2bf(p[mf][2 * rr]) |
                          ((unsigned int)f2bf(p[mf][2 * rr + 1]) << 16);
        *(unsigned int*)((char*)&Plds[wid][0] +
                         (cbase * 128 + ((mf * 32 + rgrp * 8 + rr * 4) ^ cx))) = pp;
      }
    bfx8 pf[2];
#pragma unroll
    for (int k2 = 0; k2 < 2; k2++)
      pf[k2] = *(const bfx8*)((const char*)&Plds[wid][0] +
                              (cbase * 128 + ((k2 * 64 + rgrp * 16) ^ cx)));

#pragma unroll
    for (int mb = 0; mb < 8; mb++)
#pragma unroll
      for (int k2 = 0; k2 < 2; k2++) {
        bfx8 vf = *(const bfx8*)(Vs_ + (((mb * 16 + cbase) * 128 + ((k2 * 64 + rgrp * 16) ^ cx)) >> 1));
        o[mb] = __builtin_amdgcn_mfma_f32_16x16x32_bf16(vf, pf[k2], o[mb], 0, 0, 0);
      }
    __syncthreads();
  }
#undef STAGE_T

  const float rinv = 1.0f / l_run;
  unsigned short* aop = ao + ((size_t)(b * SS + qi)) * DM + h * DH + rgrp * 4;
#pragma unroll
  for (int mb = 0; mb < 8; mb++) {
    ushort4 v;
    v.x = f2bf(o[mb][0] * rinv); v.y = f2bf(o[mb][1] * rinv);
    v.z = f2bf(o[mb][2] * rinv); v.w = f2bf(o[mb][3] * rinv);
    *(ushort4*)(aop + mb * 16) = v;
  }
}

extern "C" void kernel_launch(void* const* d_in, const int* in_sizes, int n_in,
                              void* d_out, int out_size, void* d_ws, size_t ws_size,
                              hipStream_t stream) {
  (void)in_sizes; (void)n_in; (void)out_size; (void)ws_size;
  const float* x     = (const float*)d_in[0];
  const float* w_in  = (const float*)d_in[1];
  const float* w_out = (const float*)d_in[2];
  float* out = (float*)d_out;

  char* ws = (char*)d_ws;
  unsigned short* Xb  = (unsigned short*)(ws);                     // 16 MB  [4096][2048]
  unsigned short* Wit = (unsigned short*)(ws + (16ull << 20));     // 24 MB  [6144][2048]
  unsigned short* Wot = (unsigned short*)(ws + (40ull << 20));     //  8 MB  [2048][2048]
  unsigned short* Qg  = (unsigned short*)(ws + (48ull << 20));     // 16 MB  [b][h][s][d]
  unsigned short* Kg  = (unsigned short*)(ws + (64ull << 20));     // 16 MB  [b][h][s][d]
  unsigned short* Vg  = (unsigned short*)(ws + (80ull << 20));     // 16 MB  [b][h][d][s]
  unsigned short* AO  = (unsigned short*)(ws + (96ull << 20));     // 16 MB  [4096][2048]

  // fused prep: cast (8192 blocks) + w_in transpose (12288 blocks)
  prep_fused_k<<<20480, 256, 0, stream>>>(x, Xb, w_in, Wit);
  // QKV projection: 256x192 tiles, 4Mx2N wave grid -> grid 512 (exactly 2 rounds)
  gemm256_qkv_k<<<512, 512, 0, stream>>>(Xb, Wit, Qg, Kg, Vg, DM);
  // attention (1024 blocks heavy-first) + w_out transpose tail (4096 blocks)
  attn_wot_k<<<5120, 256, 0, stream>>>(Qg, Kg, Vg, AO, w_out, Wot);
  // out = AO @ Wot^T (f32): 256x128 tiles -> grid 256 (exactly 1 round)
  gemm256_out_k<<<256, 512, 0, stream>>>(AO, Wot, out, DM, DM);
}

// Round 28
// 229.323 us; speedup vs baseline: 1.0089x; 1.0089x over previous
//
#include <hip/hip_runtime.h>

// Problem constants
#define HD    16
#define DH    128
#define BB    2
#define SS    2048
#define DM    2048
#define NQKV  6144   // 3*HD*DH
#define MTOT  4096   // BB*SS

typedef short   bfx8  __attribute__((ext_vector_type(8)));   // 8 bf16 (4 VGPRs)
typedef float   f32x4 __attribute__((ext_vector_type(4)));

__device__ __forceinline__ unsigned short f2bf(float f) {
  union { float f; unsigned int u; } c; c.f = f;
  unsigned int u = c.u + 0x7FFFu + ((c.u >> 16) & 1u);
  return (unsigned short)(u >> 16);
}

__device__ __forceinline__ void gload_lds16(const unsigned short* g, unsigned short* l) {
  __builtin_amdgcn_global_load_lds(
      (const __attribute__((address_space(1))) unsigned int*)g,
      (__attribute__((address_space(3))) unsigned int*)l, 16, 0, 0);
}

// DRAINED barrier: lgkmcnt(0) before s_barrier guarantees all issued ds_reads have
// executed before any wave passes -> post-barrier global_load_lds stages cannot
// overwrite LDS regions still pending read.
#define BARS() do { asm volatile("s_waitcnt lgkmcnt(0)" ::: "memory");               \
                    __builtin_amdgcn_sched_barrier(0); __builtin_amdgcn_s_barrier(); \
                    __builtin_amdgcn_sched_barrier(0); } while (0)
#define VMCNT10() do { asm volatile("s_waitcnt vmcnt(10)" ::: "memory"); \
                       __builtin_amdgcn_sched_barrier(0); } while (0)
#define VMCNT6() do { asm volatile("s_waitcnt vmcnt(6)" ::: "memory"); \
                      __builtin_amdgcn_sched_barrier(0); } while (0)

// ---------------- fused prep: f32->bf16 cast (blocks 0..8191) + w_in transpose ----------------
__global__ __launch_bounds__(256) void prep_fused_k(const float* __restrict__ x,
                                                    unsigned short* __restrict__ Xb,
                                                    const float* __restrict__ w_in,
                                                    unsigned short* __restrict__ Wit) {
  __shared__ float t[32][33];
  const int bid = (int)blockIdx.x;
  if (bid < 8192) {
    const int i = bid * 256 + (int)threadIdx.x;
    const float4 v = *(const float4*)(x + (size_t)i * 4);
    ushort4 o;
    o.x = f2bf(v.x); o.y = f2bf(v.y); o.z = f2bf(v.z); o.w = f2bf(v.w);
    *(ushort4*)(Xb + (size_t)i * 4) = o;
    return;
  }
  const int tb = bid - 8192;
  const int c0 = (tb % 192) * 32, r0 = (tb / 192) * 32;
  const int tx = threadIdx.x & 31, ty = threadIdx.x >> 5;  // 32 x 8
#pragma unroll
  for (int i = 0; i < 4; i++) {
    int r = r0 + ty + i * 8;
    t[ty + i * 8][tx] = w_in[(size_t)r * NQKV + c0 + tx];
  }
  __syncthreads();
#pragma unroll
  for (int i = 0; i < 4; i++) {
    int c = c0 + ty + i * 8;
    Wit[(size_t)c * DM + r0 + tx] = f2bf(t[tx][ty + i * 8]);
  }
}

// ---------------- 128x192 bf16 GEMM for QKV: 2 blocks/CU, 4 waves (2M x 2N) ----------------
// LDS 80 KB (A 2x16KB, B 2x24KB) -> 2 blocks/CU; grid 1024 = one fully-resident round.
// Wave tile 64x96, acc[4][6]; 3 phases x 16 MFMA (a x b01 | a x b23 | a x b45).
// Register prefetch one phase early (ph3(u-1): A + b01). Staging: 10 single-gload
// 32-row groups into regions whose reads EXECUTED >=1 drained barrier earlier:
//   ph1: A g0-3 + B g0,g3 (b01 rows)   ph2: B g1,g4 (b23 rows)   ph3: B g2,g5 (b45 rows)
// vmcnt(10) once per tile at ph3 (in-order retirement -> all of tile u+1 resident).
// ROUND-28: identical to round-23 kernel PLUS the prologue-prefetch drain (round-25 fix),
// which explains round-23's absmax failure (prologue reads raced ph1's DMA stage).
__global__ __launch_bounds__(256, 2) void gemm128_qkv_k(const unsigned short* __restrict__ A,
                                                        const unsigned short* __restrict__ Bt,
                                                        unsigned short* __restrict__ Qg,
                                                        unsigned short* __restrict__ Kg,
                                                        unsigned short* __restrict__ Vg,
                                                        int K) {
  __shared__ __align__(16) unsigned short Asb[2][128 * 64];  // 32 KB
  __shared__ __align__(16) unsigned short Bsb[2][192 * 64];  // 48 KB
  const int tid = threadIdx.x;
  const int lane = tid & 63, wid = tid >> 6;
  const int wr = wid >> 1, wc = wid & 1;            // 2 x 2 wave grid
  const int cbase = lane & 15, rgrp = lane >> 4;
  const int bid = (int)blockIdx.x;
  const int id = (bid & 7) * 128 + (bid >> 3);      // XCD-bijective (1024 = 8*128)
  const int nb = id >> 5, mb = id & 31;             // 32 n-panels x 32 m-panels
  const size_t m0 = (size_t)mb * 128, n0 = (size_t)nb * 192;
  const int nkt = K >> 6;                           // 32 K-tiles (even)

  // stage one 32-row group (4 KB, 1 gload/thread). A: g 0..3, B: g 0..5.
#define STAGE_A32(u_, g_) do {                                                          \
    const int uc_ = ((u_) < nkt ? (u_) : (nkt - 1));                                    \
    const int r_ = tid >> 3, s_ = tid & 7;                                              \
    gload_lds16(A + (m0 + (g_) * 32 + r_) * (size_t)K + uc_ * 64 +                      \
                    (((s_ * 16) ^ ((r_ & 7) << 4)) >> 1),                               \
                &Asb[(u_) & 1][(g_) * 2048] + tid * 8); } while (0)
#define STAGE_B32(u_, g_) do {                                                          \
    const int uc_ = ((u_) < nkt ? (u_) : (nkt - 1));                                    \
    const int r_ = tid >> 3, s_ = tid & 7;                                              \
    gload_lds16(Bt + (n0 + (g_) * 32 + r_) * (size_t)K + uc_ * 64 +                     \
                    (((s_ * 16) ^ ((r_ & 7) << 4)) >> 1),                               \
                &Bsb[(u_) & 1][(g_) * 2048] + tid * 8); } while (0)

  const int axor = (cbase & 7) << 4;
  int a_off[2], b_off[2];
#pragma unroll
  for (int ks = 0; ks < 2; ks++) {
    a_off[ks] = ((wr * 64 + cbase) * 128 + ((ks * 64 + rgrp * 16) ^ axor)) >> 1;
    b_off[ks] = ((wc * 96 + cbase) * 128 + ((ks * 64 + rgrp * 16) ^ axor)) >> 1;
  }

#define RD_AALL(dst_, p_) do { _Pragma("unroll")                                         \
    for (int mf_ = 0; mf_ < 4; mf_++) { _Pragma("unroll")                                \
      for (int ks_ = 0; ks_ < 2; ks_++)                                                  \
        dst_[mf_][ks_] = *(const bfx8*)((p_) + a_off[ks_] + mf_ * 1024); } } while (0)
#define RD_BP(dst_, p_, P_) do { _Pragma("unroll")                                       \
    for (int nf_ = 0; nf_ < 2; nf_++) { _Pragma("unroll")                                \
      for (int ks_ = 0; ks_ < 2; ks_++)                                                  \
        dst_[nf_][ks_] = *(const bfx8*)((p_) + b_off[ks_] + (nf_ + (P_)) * 1024); } } while (0)

#define MFMA_P(no_, AF_, BF_) do {                                                       \
    __builtin_amdgcn_s_setprio(1);                                                      \
    _Pragma("unroll")                                                                    \
    for (int mf_ = 0; mf_ < 4; mf_++) { _Pragma("unroll")                                \
      for (int nf_ = 0; nf_ < 2; nf_++) { _Pragma("unroll")                              \
        for (int ks_ = 0; ks_ < 2; ks_++)                                                \
          acc[mf_][nf_ + (no_)] = __builtin_amdgcn_mfma_f32_16x16x32_bf16(               \
              AF_[mf_][ks_], BF_[nf_][ks_], acc[mf_][nf_ + (no_)], 0, 0, 0); } }         \
    __builtin_amdgcn_s_setprio(0); } while (0)

  f32x4 acc[4][6];
  const f32x4 z = {0.f, 0.f, 0.f, 0.f};
#pragma unroll
  for (int mf = 0; mf < 4; mf++)
#pragma unroll
    for (int nf = 0; nf < 6; nf++) acc[mf][nf] = z;

  // prologue: stage tiles 0 and 1 fully (20 loads); vmcnt(10) -> tile 0 landed
  STAGE_A32(0, 0); STAGE_A32(0, 1); STAGE_A32(0, 2); STAGE_A32(0, 3);
  STAGE_B32(0, 0); STAGE_B32(0, 1); STAGE_B32(0, 2);
  STAGE_B32(0, 3); STAGE_B32(0, 4); STAGE_B32(0, 5);
  STAGE_A32(1, 0); STAGE_A32(1, 1); STAGE_A32(1, 2); STAGE_A32(1, 3);
  STAGE_B32(1, 0); STAGE_B32(1, 1); STAGE_B32(1, 2);
  STAGE_B32(1, 3); STAGE_B32(1, 4); STAGE_B32(1, 5);
  VMCNT10();
  BARS();
  bfx8 aA[4][2], b01A[2][2], aB[4][2], b01B[2][2];
  RD_AALL(aA, &Asb[0][0]);
  RD_BP(b01A, &Bsb[0][0], 0);
  BARS();   // drain prologue prefetch reads before ph1's stage into buffer 0 (round-25 fix)

#define TILE_BODY(u_, Ac, B01c, An, B01n) do {                                           \
    const unsigned short* Bs_  = &Bsb[(u_) & 1][0];                                      \
    const unsigned short* Asn_ = &Asb[((u_) + 1) & 1][0];                                \
    const unsigned short* Bsn_ = &Bsb[((u_) + 1) & 1][0];                                \
    bfx8 b23[2][2], b45[2][2];                                                           \
    /* ph1: read b23(u); stage A(u+2) g0-3 + B(u+2) g0,g3 (b01/A reads executed at */    \
    /* prior drained barrier) */                                                         \
    RD_BP(b23, Bs_, 2);                                                                  \
    STAGE_A32((u_) + 2, 0); STAGE_A32((u_) + 2, 1);                                      \
    STAGE_A32((u_) + 2, 2); STAGE_A32((u_) + 2, 3);                                      \
    STAGE_B32((u_) + 2, 0); STAGE_B32((u_) + 2, 3);                                      \
    BARS();                                                                              \
    MFMA_P(0, Ac, B01c);                                                                 \
    /* ph2: read b45(u); stage B(u+2) g1,g4 (b23 rows, reads executed @ph1 drain) */     \
    RD_BP(b45, Bs_, 4);                                                                  \
    STAGE_B32((u_) + 2, 1); STAGE_B32((u_) + 2, 4);                                      \
    BARS();                                                                              \
    MFMA_P(2, Ac, b23);                                                                  \
    /* ph3: stage B(u+2) g2,g5 (b45 rows, reads executed @ph2 drain); vmcnt(10) -> */    \
    /* tile u+1 resident; prefetch next A + b01 */                                       \
    STAGE_B32((u_) + 2, 2); STAGE_B32((u_) + 2, 5);                                      \
    VMCNT10();                                                                           \
    BARS();                                                                              \
    RD_AALL(An, Asn_);                                                                   \
    RD_BP(B01n, Bsn_, 0);                                                                \
    MFMA_P(4, Ac, b45);                                                                  \
    BARS();                                                                              \
  } while (0)

#pragma unroll 1
  for (int u = 0; u < nkt; u += 2) {
    TILE_BODY(u,     aA, b01A, aB, b01B);
    TILE_BODY(u + 1, aB, b01B, aA, b01A);
  }
#undef TILE_BODY
#undef STAGE_A32
#undef STAGE_B32

  // ---- split epilogue: n -> (head, q/k/v, d); each 16-wide frag within one class ----
#pragma unroll
  for (int mf = 0; mf < 4; mf++)
#pragma unroll
    for (int nf = 0; nf < 6; nf++) {
      const int nn = (int)n0 + wc * 96 + nf * 16;
      const int h = nn / 384, tt = (nn >> 7) % 3;
      const int d = (nn & 127) + cbase;
      const int row0 = (int)m0 + wr * 64 + mf * 16 + rgrp * 4;
      const int bb = row0 >> 11;
      const int s0 = row0 & 2047;
      if (tt == 2) {
        ushort4 v;
        v.x = f2bf(acc[mf][nf][0]); v.y = f2bf(acc[mf][nf][1]);
        v.z = f2bf(acc[mf][nf][2]); v.w = f2bf(acc[mf][nf][3]);
        *(ushort4*)(Vg + ((size_t)(bb * HD + h) * DH + d) * SS + s0) = v;
      } else {
        unsigned short* dst = (tt == 0 ? Qg : Kg);
#pragma unroll
        for (int r = 0; r < 4; r++)
          dst[((size_t)(bb * HD + h) * SS + s0 + r) * DH + d] = f2bf(acc[mf][nf][r]);
      }
    }
}

// ---------------- 256x128 bf16 GEMM for out-proj, fully drained ----------------
__global__ __launch_bounds__(512, 2) void gemm256_out_k(const unsigned short* __restrict__ A,
                                                        const unsigned short* __restrict__ Bt,
                                                        float* __restrict__ C, int K, int ldc) {
  __shared__ __align__(16) unsigned short Asb[2][256 * 64];  // 64 KB
  __shared__ __align__(16) unsigned short Bsb[2][128 * 64];  // 32 KB
  const int tid = threadIdx.x;
  const int lane = tid & 63, wid = tid >> 6;
  const int wr = wid >> 2, wc = wid & 3;            // 2 x 4 wave grid
  const int cbase = lane & 15, rgrp = lane >> 4;
  const int bid = (int)blockIdx.x;
  const int id = (bid & 7) * 32 + (bid >> 3);       // XCD-bijective (256 = 8*32)
  const int nb = id >> 4, mb = id & 15;
  const size_t m0 = (size_t)mb * 256, n0 = (size_t)nb * 128;
  const int nkt = K >> 6;                           // 32 K-tiles (even)

#define STAGE_AO(u_, g_) do {                                                           \
    const int uc_ = ((u_) < nkt ? (u_) : (nkt - 1));                                    \
    const int r_ = tid >> 3, s_ = tid & 7;                                              \
    gload_lds16(A + (m0 + (g_) * 64 + r_) * (size_t)K + uc_ * 64 +                      \
                    (((s_ * 16) ^ ((r_ & 7) << 4)) >> 1),                               \
                &Asb[(u_) & 1][(g_) * 4096] + tid * 8); } while (0)
#define STAGE_BO(u_, g_) do {                                                           \
    const int uc_ = ((u_) < nkt ? (u_) : (nkt - 1));                                    \
    const int r_ = tid >> 3, s_ = tid & 7;                                              \
    gload_lds16(Bt + (n0 + (g_) * 64 + r_) * (size_t)K + uc_ * 64 +                     \
                    (((s_ * 16) ^ ((r_ & 7) << 4)) >> 1),                               \
                &Bsb[(u_) & 1][(g_) * 4096] + tid * 8); } while (0)

  const int axor = (cbase & 7) << 4;
  int a_off[2], b_off[2];
#pragma unroll
  for (int ks = 0; ks < 2; ks++) {
    a_off[ks] = ((wr * 128 + cbase) * 128 + ((ks * 64 + rgrp * 16) ^ axor)) >> 1;
    b_off[ks] = ((wc * 32 + cbase) * 128 + ((ks * 64 + rgrp * 16) ^ axor)) >> 1;
  }

#define RD_A03(dst_, p_) do { _Pragma("unroll")                                          \
    for (int mf_ = 0; mf_ < 4; mf_++) { _Pragma("unroll")                                \
      for (int ks_ = 0; ks_ < 2; ks_++)                                                  \
        dst_[mf_][ks_] = *(const bfx8*)((p_) + a_off[ks_] + mf_ * 1024); } } while (0)
#define RD_A47(dst_, p_) do { _Pragma("unroll")                                          \
    for (int mf_ = 0; mf_ < 4; mf_++) { _Pragma("unroll")                                \
      for (int ks_ = 0; ks_ < 2; ks_++)                                                  \
        dst_[mf_][ks_] = *(const bfx8*)((p_) + a_off[ks_] + (mf_ + 4) * 1024); } } while (0)
#define RD_B01(dst_, p_) do { _Pragma("unroll")                                          \
    for (int nf_ = 0; nf_ < 2; nf_++) { _Pragma("unroll")                                \
      for (int ks_ = 0; ks_ < 2; ks_++)                                                  \
        dst_[nf_][ks_] = *(const bfx8*)((p_) + b_off[ks_] + nf_ * 1024); } } while (0)

#define MFMA_O(mo_, AF_, BF_) do {                                                       \
    __builtin_amdgcn_s_setprio(1);                                                      \
    _Pragma("unroll")                                                                    \
    for (int mf_ = 0; mf_ < 4; mf_++) { _Pragma("unroll")                                \
      for (int nf_ = 0; nf_ < 2; nf_++) { _Pragma("unroll")                              \
        for (int ks_ = 0; ks_ < 2; ks_++)                                                \
          acc[mf_ + (mo_)][nf_] = __builtin_amdgcn_mfma_f32_16x16x32_bf16(               \
              AF_[mf_][ks_], BF_[nf_][ks_], acc[mf_ + (mo_)][nf_], 0, 0, 0); } }         \
    __builtin_amdgcn_s_setprio(0); } while (0)

  f32x4 acc[8][2];
  const f32x4 z = {0.f, 0.f, 0.f, 0.f};
#pragma unroll
  for (int mf = 0; mf < 8; mf++)
#pragma unroll
    for (int nf = 0; nf < 2; nf++) acc[mf][nf] = z;

  STAGE_AO(0, 0); STAGE_AO(0, 1); STAGE_AO(0, 2); STAGE_AO(0, 3);
  STAGE_BO(0, 0); STAGE_BO(0, 1);
  STAGE_AO(1, 0); STAGE_AO(1, 1); STAGE_AO(1, 2); STAGE_AO(1, 3);
  STAGE_BO(1, 0); STAGE_BO(1, 1);
  VMCNT6();
  BARS();
  bfx8 a03A[4][2], b01A[2][2], a03B[4][2], b01B[2][2];
  RD_A03(a03A, &Asb[0][0]);
  RD_B01(b01A, &Bsb[0][0]);
  BARS();   // drain prologue prefetch reads before ph1's stage into buffer 0

#define TILE_BODY_O(u_, A03c, B01c, A03n, B01n) do {                                     \
    const unsigned short* As_  = &Asb[(u_) & 1][0];                                      \
    const unsigned short* Asn_ = &Asb[((u_) + 1) & 1][0];                                \
    const unsigned short* Bsn_ = &Bsb[((u_) + 1) & 1][0];                                \
    bfx8 a47[4][2];                                                                      \
    RD_A47(a47, As_);                                                                    \
    STAGE_AO((u_) + 2, 0); STAGE_AO((u_) + 2, 2);                                        \
    BARS();                                                                              \
    MFMA_O(0, A03c, B01c);                                                               \
    STAGE_AO((u_) + 2, 1); STAGE_AO((u_) + 2, 3);                                        \
    STAGE_BO((u_) + 2, 0); STAGE_BO((u_) + 2, 1);                                        \
    VMCNT6();                                                                            \
    BARS();                                                                              \
    RD_A03(A03n, Asn_);                                                                  \
    RD_B01(B01n, Bsn_);                                                                  \
    MFMA_O(4, a47, B01c);                                                                \
    BARS();                                                                              \
  } while (0)

#pragma unroll 1
  for (int u = 0; u < nkt; u += 2) {
    TILE_BODY_O(u,     a03A, b01A, a03B, b01B);
    TILE_BODY_O(u + 1, a03B, b01B, a03A, b01A);
  }
#undef TILE_BODY_O
#undef STAGE_AO
#undef STAGE_BO

#pragma unroll
  for (int mf = 0; mf < 8; mf++)
#pragma unroll
    for (int nf = 0; nf < 2; nf++)
#pragma unroll
      for (int r = 0; r < 4; r++) {
        size_t row = m0 + wr * 128 + mf * 16 + rgrp * 4 + r;
        size_t col = n0 + wc * 32 + nf * 16 + cbase;
        C[row * ldc + col] = acc[mf][nf][r];
      }
}

// ---------------- flash attention (blocks 0..1023) + w_out transpose tail (1024..5119) ----------
__global__ __launch_bounds__(256) void attn_wot_k(const unsigned short* __restrict__ Qg,
                                                  const unsigned short* __restrict__ Kg,
                                                  const unsigned short* __restrict__ Vg,
                                                  unsigned short* __restrict__ ao,
                                                  const float* __restrict__ w_out,
                                                  unsigned short* __restrict__ Wot) {
  __shared__ __align__(16) unsigned short Klds[2][64 * 128];   // 2 x 16 KB
  __shared__ __align__(16) unsigned short Vt[2][128 * 64];     // 2 x 16 KB
  __shared__ __align__(16) unsigned short Plds[4][16 * 64];    // 8 KB per-wave P rows
  const int tid = threadIdx.x;
  const int bid = (int)blockIdx.x;

  if (bid >= 1024) {
    float* t = (float*)&Klds[0][0];                 // 32*33 floats = 4224 B < 32 KB
    const int tb = bid - 1024;
    const int c0 = (tb & 63) * 32, r0 = (tb >> 6) * 32;
    const int tx = tid & 31, ty = tid >> 5;         // 32 x 8
#pragma unroll
    for (int i = 0; i < 4; i++) {
      int r = r0 + ty + i * 8;
      t[(ty + i * 8) * 33 + tx] = w_out[(size_t)r * DM + c0 + tx];
    }
    __syncthreads();
#pragma unroll
    for (int i = 0; i < 4; i++) {
      int c = c0 + ty + i * 8;
      Wot[(size_t)c * DM + r0 + tx] = f2bf(t[tx * 33 + ty + i * 8]);
    }
    return;
  }

  const int lane = tid & 63, wid = tid >> 6;
  const int cbase = lane & 15, rgrp = lane >> 4;
  const int cx = (cbase & 7) << 4;

  const int bh = (bid & 7) * 4 + ((bid >> 3) & 3);
  const int qt = 31 - (bid >> 5);
  const int b = bh >> 4, h = bh & 15;
  const int qbase = qt * 64;

  const unsigned short* qp0 = Qg + (size_t)(b * HD + h) * SS * DH;
  const unsigned short* kp  = Kg + (size_t)(b * HD + h) * SS * DH;
  const unsigned short* vp  = Vg + (size_t)(b * HD + h) * DH * SS;
  const float scale = 0.08838834764831845f;
  const f32x4 z = {0.f, 0.f, 0.f, 0.f};
  const int qi = qbase + wid * 16 + cbase;

  bfx8 qf[4];
  {
    const unsigned short* qp = qp0 + (size_t)qi * DH;
#pragma unroll
    for (int ks = 0; ks < 4; ks++) qf[ks] = *(const bfx8*)(qp + ks * 32 + rgrp * 8);
  }

  float m_run = -1e30f, l_run = 0.f;
  f32x4 o[8];
#pragma unroll
  for (int mb = 0; mb < 8; mb++) o[mb] = z;

#define STAGE_T(t_, s_) do {                                                        \
    const int kvb_ = (t_) * 64;                                                     \
    _Pragma("unroll")                                                               \
    for (int i_ = 0; i_ < 4; i_++) {                                                \
      int idx_ = i_ * 256 + tid;                                                    \
      int r_ = idx_ >> 4, bo_ = (idx_ & 15) * 16;                                   \
      gload_lds16(kp + (size_t)(kvb_ + r_) * DH + ((bo_ ^ ((r_ & 7) << 4)) >> 1),   \
                  &Klds[s_][idx_ * 8]);                                             \
    }                                                                               \
    _Pragma("unroll")                                                               \
    for (int i_ = 0; i_ < 4; i_++) {                                                \
      int idx_ = i_ * 256 + tid;                                                    \
      int d_ = idx_ >> 3, bo_ = (idx_ & 7) * 16;                                    \
      gload_lds16(vp + (size_t)d_ * SS + kvb_ + ((bo_ ^ ((d_ & 7) << 4)) >> 1),     \
                  &Vt[s_][idx_ * 8]);                                               \
    } } while (0)

  const int ntiles = qt + 1;
  STAGE_T(0, 0);
  __syncthreads();

  for (int t = 0; t < ntiles; ++t) {
    const int sel = t & 1;
    if (t + 1 < ntiles) STAGE_T(t + 1, sel ^ 1);
    const unsigned short* Ks_ = &Klds[sel][0];
    const unsigned short* Vs_ = &Vt[sel][0];
    const int kvb = t * 64;

    f32x4 s[4];
#pragma unroll
    for (int mf = 0; mf < 4; mf++) s[mf] = z;
#pragma unroll
    for (int mf = 0; mf < 4; mf++)
#pragma unroll
      for (int ks = 0; ks < 4; ks++) {
        bfx8 kf = *(const bfx8*)(Ks_ + (((mf * 16 + cbase) * 256 + ((ks * 64 + rgrp * 16) ^ cx)) >> 1));
        s[mf] = __builtin_amdgcn_mfma_f32_16x16x32_bf16(kf, qf[ks], s[mf], 0, 0, 0);
      }

    float sv[4][4];
    const bool diag = (t == ntiles - 1);
#pragma unroll
    for (int mf = 0; mf < 4; mf++)
#pragma unroll
      for (int r = 0; r < 4; r++) {
        float v = s[mf][r] * scale;
        if (diag && (kvb + mf * 16 + rgrp * 4 + r > qi)) v = -1e30f;
        sv[mf][r] = v;
      }
    float tm = sv[0][0];
#pragma unroll
    for (int mf = 0; mf < 4; mf++)
#pragma unroll
      for (int r = 0; r < 4; r++) tm = fmaxf(tm, sv[mf][r]);
    tm = fmaxf(tm, __shfl_xor(tm, 16));
    tm = fmaxf(tm, __shfl_xor(tm, 32));
    const float mnew = fmaxf(m_run, tm);
    float p[4][4];
    float rs = 0.f;
#pragma unroll
    for (int mf = 0; mf < 4; mf++)
#pragma unroll
      for (int r = 0; r < 4; r++) { p[mf][r] = __expf(sv[mf][r] - mnew); rs += p[mf][r]; }
    rs += __shfl_xor(rs, 16);
    rs += __shfl_xor(rs, 32);
    const float alpha = __expf(m_run - mnew);
    l_run = l_run * alpha + rs;
    m_run = mnew;
#pragma unroll
    for (int mb = 0; mb < 8; mb++)
#pragma unroll
      for (int r = 0; r < 4; r++) o[mb][r] *= alpha;

#pragma unroll
    for (int mf = 0; mf < 4; mf++)
#pragma unroll
      for (int rr = 0; rr < 2; rr++) {
        unsigned int pp = (unsigned int)f2bf(p[mf][2 * rr]) |
                          ((unsigned int)f2bf(p[mf][2 * rr + 1]) << 16);
        *(unsigned int*)((char*)&Plds[wid][0] +
                         (cbase * 128 + ((mf * 32 + rgrp * 8 + rr * 4) ^ cx))) = pp;
      }
    bfx8 pf[2];
#pragma unroll
    for (int k2 = 0; k2 < 2; k2++)
      pf[k2] = *(const bfx8*)((const char*)&Plds[wid][0] +
                              (cbase * 128 + ((k2 * 64 + rgrp * 16) ^ cx)));

#pragma unroll
    for (int mb = 0; mb < 8; mb++)
#pragma unroll
      for (int k2 = 0; k2 < 2; k2++) {
        bfx8 vf = *(const bfx8*)(Vs_ + (((mb * 16 + cbase) * 128 + ((k2 * 64 + rgrp * 16) ^ cx)) >> 1));
        o[mb] = __builtin_amdgcn_mfma_f32_16x16x32_bf16(vf, pf[k2], o[mb], 0, 0, 0);
      }
    __syncthreads();
  }
#undef STAGE_T

  const float rinv = 1.0f / l_run;
  unsigned short* aop = ao + ((size_t)(b * SS + qi)) * DM + h * DH + rgrp * 4;
#pragma unroll
  for (int mb = 0; mb < 8; mb++) {
    ushort4 v;
    v.x = f2bf(o[mb][0] * rinv); v.y = f2bf(o[mb][1] * rinv);
    v.z = f2bf(o[mb][2] * rinv); v.w = f2bf(o[mb][3] * rinv);
    *(ushort4*)(aop + mb * 16) = v;
  }
}

extern "C" void kernel_launch(void* const* d_in, const int* in_sizes, int n_in,
                              void* d_out, int out_size, void* d_ws, size_t ws_size,
                              hipStream_t stream) {
  (void)in_sizes; (void)n_in; (void)out_size; (void)ws_size;
  const float* x     = (const float*)d_in[0];
  const float* w_in  = (const float*)d_in[1];
  const float* w_out = (const float*)d_in[2];
  float* out = (float*)d_out;

  char* ws = (char*)d_ws;
  unsigned short* Xb  = (unsigned short*)(ws);                     // 16 MB  [4096][2048]
  unsigned short* Wit = (unsigned short*)(ws + (16ull << 20));     // 24 MB  [6144][2048]
  unsigned short* Wot = (unsigned short*)(ws + (40ull << 20));     //  8 MB  [2048][2048]
  unsigned short* Qg  = (unsigned short*)(ws + (48ull << 20));     // 16 MB  [b][h][s][d]
  unsigned short* Kg  = (unsigned short*)(ws + (64ull << 20));     // 16 MB  [b][h][s][d]
  unsigned short* Vg  = (unsigned short*)(ws + (80ull << 20));     // 16 MB  [b][h][d][s]
  unsigned short* AO  = (unsigned short*)(ws + (96ull << 20));     // 16 MB  [4096][2048]

  // fused prep: cast (8192 blocks) + w_in transpose (12288 blocks)
  prep_fused_k<<<20480, 256, 0, stream>>>(x, Xb, w_in, Wit);
  // QKV projection: 128x192 tiles, 2 blocks/CU -> grid 1024 (one resident round)
  gemm128_qkv_k<<<1024, 256, 0, stream>>>(Xb, Wit, Qg, Kg, Vg, DM);
  // attention (1024 blocks heavy-first) + w_out transpose tail (4096 blocks)
  attn_wot_k<<<5120, 256, 0, stream>>>(Qg, Kg, Vg, AO, w_out, Wot);
  // out = AO @ Wot^T (f32): 256x128 tiles -> grid 256 (exactly 1 round)
  gemm256_out_k<<<256, 512, 0, stream>>>(AO, Wot, out, DM, DM);
}